// Round 9
// baseline (432.972 us; speedup 1.0000x reference)
//
#include <hip/hip_runtime.h>
#include <hip/hip_bf16.h>
#include <hip/hip_fp16.h>

// adj = W@W^T (N=16384, D=128), per-row top-32, cols sorted ascending.
// out (f32, concat): [NK) row ids | [NK) sorted col idx | [NK) values.
//
//  K1 pack: LDS-transposed dual bf16 pack into MFMA fragment layout
//             addr16B(c,q) = (c>>5)*8192 + q*512 + (c&31)*16, q=kt*2+half
//           (r8 post-mortem: direct fragment-order writes were 32-line
//           scatters -> ~50us; LDS transpose makes global R and W coalesced).
//           FA = bf16(w/||w||), FB = bf16(w), plus norms.
//  K2 fused: 256 blocks x 1024 thr (16 waves = 4/SIMD; r8 ran 2/SIMD and
//           was latency-bound). RPB=64, CPS=512, NSTG=32 -> same B-traffic
//           (1.05 GB L2), 2x latency hiding. A persistent, B reg-double-
//           buffered, barrier-free K-loop, uniform threshold ZTAU (A
//           normalized). Tail (validated r5-r8): 2-level histogram brackets
//           s32; sure-in v>vhi+DELTA (value v*norm); exact f64 rescore of
//           +-DELTA window; sandwich => reference-exact selection.

#define N_ROWS 16384
#define DIM    128
#define TOPK   32
#define NK     (N_ROWS * TOPK)
#define ZTAU   2.45f
#define DELTA  0.05f
#define CAPL   192            // slots/row (mean 117, sd 10.8 -> 6.9 sigma)
#define WCAP   48
#define RPB    64             // rows per block
#define NWAVE  16
#define CPS    512            // cols per stage = 16 waves x 32
#define NSTG   (N_ROWS / CPS) // 32
#define W1BIN  0.15625f
#define W2BIN  0.00244140625f

using short8   = __attribute__((ext_vector_type(8)))  short;
using floatx16 = __attribute__((ext_vector_type(16))) float;

// ---------------- K1: LDS-transposed pack + norms ----------------
#define PK_ROWS 32
__global__ __launch_bounds__(256)
void pack_kernel(const float* __restrict__ W, unsigned short* __restrict__ FA,
                 unsigned short* __restrict__ FB, float* __restrict__ norm) {
    __shared__ float lds[PK_ROWS * 132];   // pad 132: 16B-aligned rows, low conflicts
    __shared__ float nrmS[PK_ROWS];
    const int t  = threadIdx.x;
    const int rb = blockIdx.x * PK_ROWS;

    // phase 1: coalesced row-major read -> LDS; shfl-reduce row norms
    const float4* src = (const float4*)(W + (size_t)rb * DIM);
    #pragma unroll
    for (int i = 0; i < 4; ++i) {
        const int f = t + 256 * i;                 // float4 index in 32x128 tile
        const float4 v = src[f];
        const int r = f >> 5, j = f & 31;
        *(float4*)&lds[r * 132 + j * 4] = v;
        float ss = v.x * v.x + v.y * v.y + v.z * v.z + v.w * v.w;
        #pragma unroll
        for (int off = 1; off < 32; off <<= 1) ss += __shfl_xor(ss, off, 64);
        if (j == 0) nrmS[r] = sqrtf(ss);           // threads of row r are one 32-lane half
    }
    __syncthreads();

    // phase 2: read LDS in fragment order, write FA/FB fully coalesced
    const size_t blkoff = (size_t)blockIdx.x * 8192;   // bytes per 32-row frag block
    unsigned* fa = (unsigned*)((char*)FA + blkoff);
    unsigned* fb = (unsigned*)((char*)FB + blkoff);
    #pragma unroll
    for (int i = 0; i < 8; ++i) {
        const int d   = t + 256 * i;               // output dword index, coalesced
        const int q   = d >> 7, r31 = (d >> 2) & 31, w = d & 3;
        const float f0 = lds[r31 * 132 + q * 8 + w * 2];
        const float f1 = lds[r31 * 132 + q * 8 + w * 2 + 1];
        const float inv = 1.0f / nrmS[r31];
        __hip_bfloat16 b0 = __float2bfloat16(f0), b1 = __float2bfloat16(f1);
        fb[d] = (unsigned)(*(unsigned short*)&b0) | ((unsigned)(*(unsigned short*)&b1) << 16);
        __hip_bfloat16 a0 = __float2bfloat16(f0 * inv), a1 = __float2bfloat16(f1 * inv);
        fa[d] = (unsigned)(*(unsigned short*)&a0) | ((unsigned)(*(unsigned short*)&a1) << 16);
    }
    if (t < PK_ROWS) norm[rb + t] = nrmS[t];
}

// ---------------- K2: fused score + select + write ----------------
__global__ __launch_bounds__(1024, 1)
void fused_kernel(const unsigned short* __restrict__ FA,
                  const unsigned short* __restrict__ FB,
                  const float* __restrict__ W, const float* __restrict__ norm,
                  float* __restrict__ out) {
    __shared__ unsigned int scnt[RPB];                 //   256 B
    __shared__ unsigned int candL[RPB * CAPL];         // 48 KiB
    __shared__ int          wcolS[NWAVE][WCAP];
    __shared__ double       dvalS[NWAVE][WCAP];        // hist overlays here
    __shared__ int          fcolS[NWAVE][TOPK];
    __shared__ float        fvalS[NWAVE][TOPK];
    __shared__ unsigned int wcntS[NWAVE], mcntS[NWAVE], fcntS[NWAVE];
    // static total ~62 KiB

    const int tid = threadIdx.x, lane = tid & 63, wid = tid >> 6;
    const int half = lane >> 5, l31 = lane & 31;
    const int rowbase = blockIdx.x * RPB;

    if (tid < RPB) scnt[tid] = 0u;
    __syncthreads();

    // A-frags, persistent: coalesced 1 KiB loads from fragment-layout FA
    short8 afrag[2][8];
    #pragma unroll
    for (int mt = 0; mt < 2; ++mt) {
        const char* ab = (const char*)FA + (size_t)((rowbase >> 5) + mt) * 8192
                       + half * 512 + l31 * 16;
        #pragma unroll
        for (int kt = 0; kt < 8; ++kt) afrag[mt][kt] = *(const short8*)(ab + kt * 1024);
    }

    const int rbh = 4 * half;                          // C/D row=(r&3)+8*(r>>2)+4*half
    // B stream: stage s covers cols [s*512, +512); wave wid owns col-block s*16+wid
    const char* bstream = (const char*)FB + (size_t)wid * 8192 + half * 512 + l31 * 16;

    auto step = [&](const short8* bfr, int s) {
        floatx16 acc0 = (floatx16)0.0f, acc1 = (floatx16)0.0f;
        #pragma unroll
        for (int kt = 0; kt < 8; ++kt) {
            acc0 = __builtin_amdgcn_mfma_f32_32x32x16_bf16(afrag[0][kt], bfr[kt], acc0, 0, 0, 0);
            acc1 = __builtin_amdgcn_mfma_f32_32x32x16_bf16(afrag[1][kt], bfr[kt], acc1, 0, 0, 0);
        }
        const unsigned pcol = (unsigned)(s * CPS + wid * 32 + l31) << 16;
        #pragma unroll
        for (int r = 0; r < 16; ++r) {
            if (acc0[r] > ZTAU) {
                const int rloc = rbh + (r & 3) + 8 * (r >> 2);
                unsigned slot = atomicAdd(&scnt[rloc], 1u);
                if (slot < CAPL)
                    candL[rloc * CAPL + slot] = pcol | __half_as_ushort(__float2half(acc0[r]));
            }
            if (acc1[r] > ZTAU) {
                const int rloc = 32 + rbh + (r & 3) + 8 * (r >> 2);
                unsigned slot = atomicAdd(&scnt[rloc], 1u);
                if (slot < CAPL)
                    candL[rloc * CAPL + slot] = pcol | __half_as_ushort(__float2half(acc1[r]));
            }
        }
    };

    // register double-buffered, barrier-free K-loop (100 VGPR at r8)
    short8 bX[8], bY[8];
    #pragma unroll
    for (int kt = 0; kt < 8; ++kt) bX[kt] = *(const short8*)(bstream + kt * 1024);
    for (int s = 0; s < NSTG; s += 2) {
        const char* p1 = bstream + (size_t)(s + 1) * 131072;
        #pragma unroll
        for (int kt = 0; kt < 8; ++kt) bY[kt] = *(const short8*)(p1 + kt * 1024);
        step(bX, s);
        if (s + 2 < NSTG) {
            const char* p2 = bstream + (size_t)(s + 2) * 131072;
            #pragma unroll
            for (int kt = 0; kt < 8; ++kt) bX[kt] = *(const short8*)(p2 + kt * 1024);
        }
        step(bY, s + 1);
    }
    __syncthreads();

    // -------- tail: wave wid owns rows wid*4 .. wid*4+3 (validated r5-r8) --------
    unsigned int* histW = (unsigned int*)&dvalS[wid][0];   // overlay (dead here)
    for (int rr = 0; rr < 4; ++rr) {
        const int rloc = wid * 4 + rr;
        const int rowg = rowbase + rloc;
        int n = (int)scnt[rloc]; if (n > CAPL) n = CAPL;
        const unsigned int* cl = &candL[rloc * CAPL];

        if (lane == 0) { wcntS[wid] = 0u; mcntS[wid] = 0u; fcntS[wid] = 0u; }
        // level-1 histogram over [ZTAU, ZTAU+10)
        histW[lane] = 0u;
        for (int i = lane; i < n; i += 64) {
            const float v = __half2float(__ushort_as_half((unsigned short)(cl[i] & 0xFFFFu)));
            int b = (int)((v - ZTAU) * (1.0f / W1BIN));
            b = b < 0 ? 0 : (b > 63 ? 63 : b);
            atomicAdd(&histW[b], 1u);
        }
        unsigned sfx = histW[lane];
        #pragma unroll
        for (int off = 1; off < 64; off <<= 1) {
            unsigned u = __shfl_down(sfx, off, 64);
            if (lane + off < 64) sfx += u;
        }
        unsigned long long mk = __ballot(sfx >= (unsigned)TOPK);
        const int b1 = mk ? (63 - __clzll(mk)) : 0;
        unsigned Gup = __shfl(sfx, (b1 + 1) & 63, 64);
        if (b1 == 63) Gup = 0u;
        const float lo1 = ZTAU + (float)b1 * W1BIN;

        // level-2 histogram within [lo1, lo1+W1BIN)
        histW[lane] = 0u;
        for (int i = lane; i < n; i += 64) {
            const float v = __half2float(__ushort_as_half((unsigned short)(cl[i] & 0xFFFFu)));
            if (v >= lo1 && v < lo1 + W1BIN) {
                int b = (int)((v - lo1) * (1.0f / W2BIN));
                b = b < 0 ? 0 : (b > 63 ? 63 : b);
                atomicAdd(&histW[b], 1u);
            }
        }
        unsigned sfx2 = histW[lane];
        #pragma unroll
        for (int off = 1; off < 64; off <<= 1) {
            unsigned u = __shfl_down(sfx2, off, 64);
            if (lane + off < 64) sfx2 += u;
        }
        sfx2 += Gup;
        mk = __ballot(sfx2 >= (unsigned)TOPK);
        const int b2 = mk ? (63 - __clzll(mk)) : 0;
        const float vlo = lo1 + (float)b2 * W2BIN;       // s32 in [vlo, vhi)
        const float vhi = vlo + W2BIN;

        // classify: sure-in / window
        for (int i = lane; i < n; i += 64) {
            const unsigned e = cl[i];
            const float v = __half2float(__ushort_as_half((unsigned short)(e & 0xFFFFu)));
            if (v > vhi + DELTA) {
                atomicAdd(&mcntS[wid], 1u);
            } else if (v >= vlo - DELTA) {
                unsigned u = atomicAdd(&wcntS[wid], 1u);
                if (u < WCAP) wcolS[wid][u] = (int)(e >> 16);
            }
        }
        const int m = (int)mcntS[wid];
        int wn = (int)wcntS[wid]; if (wn > WCAP) wn = WCAP;
        int need = TOPK - m; if (need < 0) need = 0;

        // exact f64 rescore of window, one member per lane (parallel gather)
        if (lane < wn) {
            const int col = wcolS[wid][lane] & (N_ROWS - 1);
            const float4* wa = (const float4*)(W + (size_t)rowg * DIM);
            const float4* wb = (const float4*)(W + (size_t)col * DIM);
            double d0 = 0, d1 = 0, d2 = 0, d3 = 0;
            #pragma unroll
            for (int k = 0; k < DIM / 4; ++k) {
                const float4 x = wa[k]; const float4 y = wb[k];
                d0 += (double)x.x * y.x; d1 += (double)x.y * y.y;
                d2 += (double)x.z * y.z; d3 += (double)x.w * y.w;
            }
            dvalS[wid][lane] = (d0 + d1) + (d2 + d3);
        }
        // top-`need` of window by (exact desc, col asc)
        if (lane < wn) {
            const double dv = dvalS[wid][lane]; const int c = wcolS[wid][lane];
            int r = 0;
            for (int u = 0; u < wn; ++u) {
                const double du = dvalS[wid][u];
                r += (du > dv || (du == dv && wcolS[wid][u] < c)) ? 1 : 0;
            }
            if (r < need) {
                unsigned slot = atomicAdd(&fcntS[wid], 1u);
                if (slot < TOPK) { fcolS[wid][slot] = c; fvalS[wid][slot] = (float)dv; }
            }
        }
        // sure-ins: value = stored fp16 score * norm (validated r6-r8)
        const float nm = norm[rowg];
        for (int i = lane; i < n; i += 64) {
            const unsigned e = cl[i];
            const float v = __half2float(__ushort_as_half((unsigned short)(e & 0xFFFFu)));
            if (v > vhi + DELTA) {
                unsigned slot = atomicAdd(&fcntS[wid], 1u);
                if (slot < TOPK) { fcolS[wid][slot] = (int)(e >> 16); fvalS[wid][slot] = v * nm; }
            }
        }
        int fn = (int)fcntS[wid]; if (fn > TOPK) fn = TOPK;
        // sort <=32 finalists by col, write all 3 segments
        if (lane < fn) {
            const int c = fcolS[wid][lane];
            int pos = 0;
            for (int j = 0; j < fn; ++j) pos += (fcolS[wid][j] < c) ? 1 : 0;
            const size_t base = (size_t)rowg * TOPK + pos;
            out[base]                  = (float)rowg;
            out[NK + base]             = (float)c;
            out[2 * (size_t)NK + base] = fvalS[wid][lane];
        }
    }
}

extern "C" void kernel_launch(void* const* d_in, const int* in_sizes, int n_in,
                              void* d_out, int out_size, void* d_ws, size_t ws_size,
                              hipStream_t stream) {
    (void)in_sizes; (void)n_in; (void)out_size; (void)ws_size;
    const float* W   = (const float*)d_in[1];        // d_in[0] = x (unused)
    float*       out = (float*)d_out;

    char* ws = (char*)d_ws;                          // ~8.1 MiB used
    unsigned short* FA   = (unsigned short*)ws;                      // 4 MiB normalized, frag layout
    unsigned short* FB   = (unsigned short*)(ws + (size_t)4194304);  // 4 MiB raw, frag layout
    float*          norm = (float*)(ws + (size_t)8388608);           // 64 KiB

    pack_kernel<<<N_ROWS / PK_ROWS, 256, 0, stream>>>(W, FA, FB, norm);
    fused_kernel<<<N_ROWS / RPB, 1024, 0, stream>>>(FA, FB, W, norm, out);
}

// Round 10
// 226.089 us; speedup vs baseline: 1.9150x; 1.9150x over previous
//
#include <hip/hip_runtime.h>
#include <hip/hip_bf16.h>
#include <hip/hip_fp16.h>

// adj = W@W^T (N=16384, D=128), per-row top-32, cols sorted ascending.
// out (f32, concat): [NK) row ids | [NK) sorted col idx | [NK) values.
//
//  K1 pack: LDS-transposed dual bf16 pack into MFMA fragment layout
//             addr16B(c,q) = (c>>5)*8192 + q*512 + (c&31)*16, q=kt*2+half
//           -> K2 fragment loads are contiguous 1 KiB wave transactions.
//           FA = bf16(w/||w||), FB = bf16(w), plus norms.
//  K2 fused: RPB=32 rows/block, 512 thr (8 waves), grid 512 = 2 blocks/CU
//           (r9 post-mortem: 1024-thr/16-wave forced a 64-VGPR budget and
//           spilled the frag registers to scratch -> 866 MB FETCH. This
//           round: small register set ~95 regs, launch_bounds(512,4),
//           occupancy via 2 blocks/CU instead of bigger blocks).
//           Single-buffered B (no bY), TLP covers L2 latency. Uniform
//           threshold ZTAU (A normalized). Tail (validated r5-r9):
//           2-level histogram brackets s32; sure-in v>vhi+DELTA (value
//           v*norm); exact f64 rescore of +-DELTA window; sandwich =>
//           reference-exact selection.

#define N_ROWS 16384
#define DIM    128
#define TOPK   32
#define NK     (N_ROWS * TOPK)
#define ZTAU   2.45f
#define DELTA  0.05f
#define CAPL   192            // slots/row (mean 117, sd 10.8 -> 6.9 sigma)
#define WCAP   48
#define RPB    32             // rows per block
#define NWAVE  8
#define CPS    256            // cols per stage = 8 waves x 32
#define NSTG   (N_ROWS / CPS) // 64
#define W1BIN  0.15625f
#define W2BIN  0.00244140625f

using short8   = __attribute__((ext_vector_type(8)))  short;
using floatx16 = __attribute__((ext_vector_type(16))) float;

// ---------------- K1: LDS-transposed pack + norms ----------------
#define PK_ROWS 32
__global__ __launch_bounds__(256)
void pack_kernel(const float* __restrict__ W, unsigned short* __restrict__ FA,
                 unsigned short* __restrict__ FB, float* __restrict__ norm) {
    __shared__ float lds[PK_ROWS * 132];
    __shared__ float nrmS[PK_ROWS];
    const int t  = threadIdx.x;
    const int rb = blockIdx.x * PK_ROWS;

    // phase 1: coalesced row-major read -> LDS; shfl-reduce row norms
    const float4* src = (const float4*)(W + (size_t)rb * DIM);
    #pragma unroll
    for (int i = 0; i < 4; ++i) {
        const int f = t + 256 * i;                 // float4 index in 32x128 tile
        const float4 v = src[f];
        const int r = f >> 5, j = f & 31;
        *(float4*)&lds[r * 132 + j * 4] = v;
        float ss = v.x * v.x + v.y * v.y + v.z * v.z + v.w * v.w;
        #pragma unroll
        for (int off = 1; off < 32; off <<= 1) ss += __shfl_xor(ss, off, 64);
        if (j == 0) nrmS[r] = sqrtf(ss);
    }
    __syncthreads();

    // phase 2: read LDS in fragment order, write FA/FB fully coalesced
    const size_t blkoff = (size_t)blockIdx.x * 8192;
    unsigned* fa = (unsigned*)((char*)FA + blkoff);
    unsigned* fb = (unsigned*)((char*)FB + blkoff);
    #pragma unroll
    for (int i = 0; i < 8; ++i) {
        const int d   = t + 256 * i;               // output dword index, coalesced
        const int q   = d >> 7, r31 = (d >> 2) & 31, w = d & 3;
        const float f0 = lds[r31 * 132 + q * 8 + w * 2];
        const float f1 = lds[r31 * 132 + q * 8 + w * 2 + 1];
        const float inv = 1.0f / nrmS[r31];
        __hip_bfloat16 b0 = __float2bfloat16(f0), b1 = __float2bfloat16(f1);
        fb[d] = (unsigned)(*(unsigned short*)&b0) | ((unsigned)(*(unsigned short*)&b1) << 16);
        __hip_bfloat16 a0 = __float2bfloat16(f0 * inv), a1 = __float2bfloat16(f1 * inv);
        fa[d] = (unsigned)(*(unsigned short*)&a0) | ((unsigned)(*(unsigned short*)&a1) << 16);
    }
    if (t < PK_ROWS) norm[rb + t] = nrmS[t];
}

// ---------------- K2: fused score + select + write ----------------
__global__ __launch_bounds__(512, 4)
void fused_kernel(const unsigned short* __restrict__ FA,
                  const unsigned short* __restrict__ FB,
                  const float* __restrict__ W, const float* __restrict__ norm,
                  float* __restrict__ out) {
    __shared__ unsigned int scnt[RPB];                 //   128 B
    __shared__ unsigned int candL[RPB * CAPL];         // 24 KiB
    __shared__ int          wcolS[NWAVE][WCAP];
    __shared__ double       dvalS[NWAVE][WCAP];        // hist overlays here
    __shared__ int          fcolS[NWAVE][TOPK];
    __shared__ float        fvalS[NWAVE][TOPK];
    __shared__ unsigned int wcntS[NWAVE], mcntS[NWAVE], fcntS[NWAVE];
    // static total ~31 KiB -> 2 blocks/CU

    const int tid = threadIdx.x, lane = tid & 63, wid = tid >> 6;   // wid 0..7
    const int half = lane >> 5, l31 = lane & 31;
    const int rowbase = blockIdx.x * RPB;

    if (tid < RPB) scnt[tid] = 0u;
    __syncthreads();

    // A-frags (single 32-row m-tile), persistent: coalesced 1 KiB loads
    short8 afrag[8];
    {
        const char* ab = (const char*)FA + (size_t)(rowbase >> 5) * 8192
                       + half * 512 + l31 * 16;
        #pragma unroll
        for (int kt = 0; kt < 8; ++kt) afrag[kt] = *(const short8*)(ab + kt * 1024);
    }

    const int rbh = 4 * half;                          // C/D row=(r&3)+8*(r>>2)+4*half
    // wave wid owns col-block cb = s*8 + wid  (cols s*256 + wid*32 ..+32)
    const char* bstream = (const char*)FB + (size_t)wid * 8192 + half * 512 + l31 * 16;

    for (int s = 0; s < NSTG; ++s) {
        const char* bp = bstream + (size_t)s * 65536;
        short8 bfr[8];
        #pragma unroll
        for (int kt = 0; kt < 8; ++kt) bfr[kt] = *(const short8*)(bp + kt * 1024);
        floatx16 acc = (floatx16)0.0f;
        #pragma unroll
        for (int kt = 0; kt < 8; ++kt)
            acc = __builtin_amdgcn_mfma_f32_32x32x16_bf16(afrag[kt], bfr[kt], acc, 0, 0, 0);
        const unsigned pcol = (unsigned)(s * CPS + wid * 32 + l31) << 16;
        #pragma unroll
        for (int r = 0; r < 16; ++r) {
            if (acc[r] > ZTAU) {
                const int rloc = rbh + (r & 3) + 8 * (r >> 2);
                unsigned slot = atomicAdd(&scnt[rloc], 1u);
                if (slot < CAPL)
                    candL[rloc * CAPL + slot] = pcol | __half_as_ushort(__float2half(acc[r]));
            }
        }
    }
    __syncthreads();

    // -------- tail: wave wid owns rows wid*4 .. wid*4+3 (validated r5-r9) --------
    unsigned int* histW = (unsigned int*)&dvalS[wid][0];   // overlay (dead here)
    for (int rr = 0; rr < 4; ++rr) {
        const int rloc = wid * 4 + rr;
        const int rowg = rowbase + rloc;
        int n = (int)scnt[rloc]; if (n > CAPL) n = CAPL;
        const unsigned int* cl = &candL[rloc * CAPL];

        if (lane == 0) { wcntS[wid] = 0u; mcntS[wid] = 0u; fcntS[wid] = 0u; }
        // level-1 histogram over [ZTAU, ZTAU+10)
        histW[lane] = 0u;
        for (int i = lane; i < n; i += 64) {
            const float v = __half2float(__ushort_as_half((unsigned short)(cl[i] & 0xFFFFu)));
            int b = (int)((v - ZTAU) * (1.0f / W1BIN));
            b = b < 0 ? 0 : (b > 63 ? 63 : b);
            atomicAdd(&histW[b], 1u);
        }
        unsigned sfx = histW[lane];
        #pragma unroll
        for (int off = 1; off < 64; off <<= 1) {
            unsigned u = __shfl_down(sfx, off, 64);
            if (lane + off < 64) sfx += u;
        }
        unsigned long long mk = __ballot(sfx >= (unsigned)TOPK);
        const int b1 = mk ? (63 - __clzll(mk)) : 0;
        unsigned Gup = __shfl(sfx, (b1 + 1) & 63, 64);
        if (b1 == 63) Gup = 0u;
        const float lo1 = ZTAU + (float)b1 * W1BIN;

        // level-2 histogram within [lo1, lo1+W1BIN)
        histW[lane] = 0u;
        for (int i = lane; i < n; i += 64) {
            const float v = __half2float(__ushort_as_half((unsigned short)(cl[i] & 0xFFFFu)));
            if (v >= lo1 && v < lo1 + W1BIN) {
                int b = (int)((v - lo1) * (1.0f / W2BIN));
                b = b < 0 ? 0 : (b > 63 ? 63 : b);
                atomicAdd(&histW[b], 1u);
            }
        }
        unsigned sfx2 = histW[lane];
        #pragma unroll
        for (int off = 1; off < 64; off <<= 1) {
            unsigned u = __shfl_down(sfx2, off, 64);
            if (lane + off < 64) sfx2 += u;
        }
        sfx2 += Gup;
        mk = __ballot(sfx2 >= (unsigned)TOPK);
        const int b2 = mk ? (63 - __clzll(mk)) : 0;
        const float vlo = lo1 + (float)b2 * W2BIN;       // s32 in [vlo, vhi)
        const float vhi = vlo + W2BIN;

        // classify: sure-in / window
        for (int i = lane; i < n; i += 64) {
            const unsigned e = cl[i];
            const float v = __half2float(__ushort_as_half((unsigned short)(e & 0xFFFFu)));
            if (v > vhi + DELTA) {
                atomicAdd(&mcntS[wid], 1u);
            } else if (v >= vlo - DELTA) {
                unsigned u = atomicAdd(&wcntS[wid], 1u);
                if (u < WCAP) wcolS[wid][u] = (int)(e >> 16);
            }
        }
        const int m = (int)mcntS[wid];
        int wn = (int)wcntS[wid]; if (wn > WCAP) wn = WCAP;
        int need = TOPK - m; if (need < 0) need = 0;

        // exact f64 rescore of window, one member per lane (parallel gather)
        if (lane < wn) {
            const int col = wcolS[wid][lane] & (N_ROWS - 1);
            const float4* wa = (const float4*)(W + (size_t)rowg * DIM);
            const float4* wb = (const float4*)(W + (size_t)col * DIM);
            double d0 = 0, d1 = 0, d2 = 0, d3 = 0;
            #pragma unroll
            for (int k = 0; k < DIM / 4; ++k) {
                const float4 x = wa[k]; const float4 y = wb[k];
                d0 += (double)x.x * y.x; d1 += (double)x.y * y.y;
                d2 += (double)x.z * y.z; d3 += (double)x.w * y.w;
            }
            dvalS[wid][lane] = (d0 + d1) + (d2 + d3);
        }
        // top-`need` of window by (exact desc, col asc)
        if (lane < wn) {
            const double dv = dvalS[wid][lane]; const int c = wcolS[wid][lane];
            int r = 0;
            for (int u = 0; u < wn; ++u) {
                const double du = dvalS[wid][u];
                r += (du > dv || (du == dv && wcolS[wid][u] < c)) ? 1 : 0;
            }
            if (r < need) {
                unsigned slot = atomicAdd(&fcntS[wid], 1u);
                if (slot < TOPK) { fcolS[wid][slot] = c; fvalS[wid][slot] = (float)dv; }
            }
        }
        // sure-ins: value = stored fp16 score * norm (validated r6-r9)
        const float nm = norm[rowg];
        for (int i = lane; i < n; i += 64) {
            const unsigned e = cl[i];
            const float v = __half2float(__ushort_as_half((unsigned short)(e & 0xFFFFu)));
            if (v > vhi + DELTA) {
                unsigned slot = atomicAdd(&fcntS[wid], 1u);
                if (slot < TOPK) { fcolS[wid][slot] = (int)(e >> 16); fvalS[wid][slot] = v * nm; }
            }
        }
        int fn = (int)fcntS[wid]; if (fn > TOPK) fn = TOPK;
        // sort <=32 finalists by col, write all 3 segments
        if (lane < fn) {
            const int c = fcolS[wid][lane];
            int pos = 0;
            for (int j = 0; j < fn; ++j) pos += (fcolS[wid][j] < c) ? 1 : 0;
            const size_t base = (size_t)rowg * TOPK + pos;
            out[base]                  = (float)rowg;
            out[NK + base]             = (float)c;
            out[2 * (size_t)NK + base] = fvalS[wid][lane];
        }
    }
}

extern "C" void kernel_launch(void* const* d_in, const int* in_sizes, int n_in,
                              void* d_out, int out_size, void* d_ws, size_t ws_size,
                              hipStream_t stream) {
    (void)in_sizes; (void)n_in; (void)out_size; (void)ws_size;
    const float* W   = (const float*)d_in[1];        // d_in[0] = x (unused)
    float*       out = (float*)d_out;

    char* ws = (char*)d_ws;                          // ~8.1 MiB used
    unsigned short* FA   = (unsigned short*)ws;                      // 4 MiB normalized, frag layout
    unsigned short* FB   = (unsigned short*)(ws + (size_t)4194304);  // 4 MiB raw, frag layout
    float*          norm = (float*)(ws + (size_t)8388608);           // 64 KiB

    pack_kernel<<<N_ROWS / PK_ROWS, 256, 0, stream>>>(W, FA, FB, norm);
    fused_kernel<<<N_ROWS / RPB, 512, 0, stream>>>(FA, FB, W, norm, out);
}